// Round 8
// baseline (516.368 us; speedup 1.0000x reference)
//
#include <hip/hip_runtime.h>
#include <cmath>

// SimplicialAttentionLayer: out = softmax((H Wq)(H Wk)^T * A / sqrt(D)) @ (H Wv)
// N=8192, D=512, fp32. Split-precision bf16 MFMA pipeline.
//  gemm_bt<0,3,1,1>: fused 3-projection GEMM -> HQ/HK/HV hi/lo (128x128, proven)
//  k_big<2,3,1>: scores 3-pass, 256x128 tile, wave tile 128x64 (2 blk/CU):
//                raises MFMA/LDS-byte ratio 3->4 vs R7. Per-wave chunk softmax.
//  k_big<3,1,4>: PV 1-pass, same geometry, F folded into staging, K-split 4-way
//  k_reduce / k_sumout3: softmax fixup + partial fold

typedef unsigned short u16;
typedef unsigned int   u32;
typedef float f32x4 __attribute__((ext_vector_type(4)));
typedef short s16x8 __attribute__((ext_vector_type(8)));

#define DEVI static __device__ __forceinline__

DEVI u16 f2bf(float x) { u32 u = __float_as_uint(x); u32 r = u + 0x7fffu + ((u >> 16) & 1u); return (u16)(r >> 16); }
DEVI float bf2f(u16 b) { return __uint_as_float((u32)b << 16); }

DEVI f32x4 mm_bf16(s16x8 a, s16x8 b, f32x4 c) {
  return __builtin_amdgcn_mfma_f32_16x16x32_bf16(a, b, c, 0, 0, 0);
}

// scale 8 packed bf16 by f, round-nearest, repack via v_perm
DEVI uint4 scaleP(uint4 v, float f) {
  u32* w = (u32*)&v;
#pragma unroll
  for (int j = 0; j < 4; j++) {
    u32 lo = __float_as_uint(__uint_as_float(w[j] << 16) * f) + 0x8000u;
    u32 hi = __float_as_uint(__uint_as_float(w[j] & 0xffff0000u) * f) + 0x8000u;
    w[j] = __builtin_amdgcn_perm(hi, lo, 0x07060302);
  }
  return v;
}

// ---------------- elementwise prep kernels ----------------

__global__ void k_split(const float* __restrict__ X, u16* __restrict__ Xhi, u16* __restrict__ Xlo, int n4) {
  int i = blockIdx.x * 256 + threadIdx.x;
  if (i >= n4) return;
  float4 v = ((const float4*)X)[i];
  u16 h0 = f2bf(v.x), h1 = f2bf(v.y), h2 = f2bf(v.z), h3 = f2bf(v.w);
  u16 l0 = f2bf(v.x - bf2f(h0)), l1 = f2bf(v.y - bf2f(h1));
  u16 l2 = f2bf(v.z - bf2f(h2)), l3 = f2bf(v.w - bf2f(h3));
  ((uint2*)Xhi)[i] = make_uint2((u32)h0 | ((u32)h1 << 16), (u32)h2 | ((u32)h3 << 16));
  ((uint2*)Xlo)[i] = make_uint2((u32)l0 | ((u32)l1 << 16), (u32)l2 | ((u32)l3 << 16));
}

__global__ void k_prepW(const float* __restrict__ W0, const float* __restrict__ W1, const float* __restrict__ W2,
                        u16* __restrict__ Thi, u16* __restrict__ Tlo) {
  int idx = blockIdx.x * 256 + threadIdx.x;
  if (idx >= 3 * 512 * 512) return;
  int w = idx >> 18, n = (idx >> 9) & 511, k = idx & 511;
  const float* W = (w == 0) ? W0 : (w == 1) ? W1 : W2;
  float v = W[k * 512 + n];
  u16 h = f2bf(v);
  Thi[idx] = h;
  Tlo[idx] = f2bf(v - bf2f(h));
}

__global__ void k_transpose(const u16* __restrict__ in, u16* __restrict__ out, int R, int C) {
  __shared__ u16 t[64][72];
  const int rb = blockIdx.x * 64, cb = blockIdx.y * 64;
  const int r = threadIdx.x >> 2, c4 = (threadIdx.x & 3) * 16;
  const u16* src = in + (size_t)(rb + r) * C + cb + c4;
  *(uint4*)&t[r][c4] = *(const uint4*)src;
  *(uint4*)&t[r][c4 + 8] = *(const uint4*)(src + 8);
  __syncthreads();
  u16 v[16];
#pragma unroll
  for (int j = 0; j < 16; j++) v[j] = t[c4 + j][r];
  uint4 o0, o1;
  o0.x = v[0] | ((u32)v[1] << 16); o0.y = v[2] | ((u32)v[3] << 16);
  o0.z = v[4] | ((u32)v[5] << 16); o0.w = v[6] | ((u32)v[7] << 16);
  o1.x = v[8] | ((u32)v[9] << 16); o1.y = v[10] | ((u32)v[11] << 16);
  o1.z = v[12] | ((u32)v[13] << 16); o1.w = v[14] | ((u32)v[15] << 16);
  u16* dst = out + (size_t)(cb + r) * R + rb + c4;
  *(uint4*)dst = o0;
  *(uint4*)(dst + 8) = o1;
}

// ---------------- k_big: 256x128 tile, 4 waves, wave tile 128x64 ----------------
// C = A @ B^T, A [M][K], B [N][K] row-major bf16 hi/lo. 2 blocks/CU.
// EPI: 2 = scores epilogue (mask*scale, per-wave 128-kv chunk softmax, P' bf16)
//      3 = fp32 C with F-scaled A staging (PV), KSPLIT partials
// PASSES: 3 = AhBh+AhBl+AlBh ; 1 = AhBh

template<int EPI, int PASSES, int KSPLIT>
__launch_bounds__(256, 2)
__global__ void k_big(const u16* __restrict__ Ahi, const u16* __restrict__ Alo,
                      const u16* __restrict__ Bhi, const u16* __restrict__ Blo,
                      int M, int N, int K,
                      float* __restrict__ Cf, float* __restrict__ Cf1,
                      float* __restrict__ Cf2, float* __restrict__ Cf3,
                      const float* __restrict__ Adj, float* __restrict__ mC,
                      float* __restrict__ lC, u16* __restrict__ Pout,
                      const float* __restrict__ Fsc, float scale)
{
  // stage: sAh[256][40] sAl[256][40] sBh[128][40] sBl[128][40] (P3: 30720 u16)
  // EPI2 epilogue reuses lds as pb[128][264] (33792 u16 = 67584 B)
  constexpr int LDSU = (EPI == 2) ? 33792 : 15360;
  __shared__ __align__(16) u16 lds[LDSU];
  u16* sAh = lds;
  u16* sAl = lds + 10240;                                   // P3 only
  u16* sBh = lds + ((PASSES == 3) ? 20480 : 10240);
  u16* sBl = lds + 25600;                                   // P3 only

  const int tid = threadIdx.x, lane = tid & 63, wid = tid >> 6;
  const int wn = wid & 1, wm = wid >> 1;       // wave tile: m [wm*128,+128) x n [wn*64,+64)
  const int lr = lane & 15, lk = lane >> 4;
  const int mbase = blockIdx.x * 256, nbase = blockIdx.y * 128;
  const int srow = tid >> 1, shalf = tid & 1;  // staging: 2 thr/row, 32 B each
  const size_t Ks = (size_t)K;

  int kbeg = 0, kend = K;
  if constexpr (KSPLIT > 1) {
    const int steps = K >> 5, bz = blockIdx.z;
    kbeg = ((steps * bz) / KSPLIT) << 5;
    kend = ((steps * (bz + 1)) / KSPLIT) << 5;
  }

  f32x4 acc[8][4] = {};

  for (int kt = kbeg; kt < kend; kt += 32) {
    const size_t a0 = (size_t)(mbase + srow) * Ks + kt + shalf * 16;
    const size_t a1 = a0 + (size_t)128 * Ks;
    const size_t b0 = (size_t)(nbase + srow) * Ks + kt + shalf * 16;
    uint4 vah0 = *(const uint4*)(Ahi + a0), vah1 = *(const uint4*)(Ahi + a0 + 8);
    uint4 vah2 = *(const uint4*)(Ahi + a1), vah3 = *(const uint4*)(Ahi + a1 + 8);
    uint4 vbh0 = *(const uint4*)(Bhi + b0), vbh1 = *(const uint4*)(Bhi + b0 + 8);
    uint4 val0, val1, val2, val3, vbl0, vbl1;
    if constexpr (PASSES == 3) {
      val0 = *(const uint4*)(Alo + a0); val1 = *(const uint4*)(Alo + a0 + 8);
      val2 = *(const uint4*)(Alo + a1); val3 = *(const uint4*)(Alo + a1 + 8);
      vbl0 = *(const uint4*)(Blo + b0); vbl1 = *(const uint4*)(Blo + b0 + 8);
    }
    if constexpr (EPI == 3) {  // fold softmax fixup F into P staging
      const float f0 = Fsc[((size_t)(kt >> 7) << 13) + mbase + srow];
      const float f1 = Fsc[((size_t)(kt >> 7) << 13) + mbase + 128 + srow];
      vah0 = scaleP(vah0, f0); vah1 = scaleP(vah1, f0);
      vah2 = scaleP(vah2, f1); vah3 = scaleP(vah3, f1);
    }
    __syncthreads();
    const int so = srow * 40 + shalf * 16;
    *(uint4*)(sAh + so) = vah0;        *(uint4*)(sAh + so + 8) = vah1;
    *(uint4*)(sAh + 5120 + so) = vah2; *(uint4*)(sAh + 5120 + so + 8) = vah3;
    *(uint4*)(sBh + so) = vbh0;        *(uint4*)(sBh + so + 8) = vbh1;
    if constexpr (PASSES == 3) {
      *(uint4*)(sAl + so) = val0;        *(uint4*)(sAl + so + 8) = val1;
      *(uint4*)(sAl + 5120 + so) = val2; *(uint4*)(sAl + 5120 + so + 8) = val3;
      *(uint4*)(sBl + so) = vbl0;        *(uint4*)(sBl + so + 8) = vbl1;
    }
    __syncthreads();

    s16x8 ah[8], al[8];
#pragma unroll
    for (int m = 0; m < 8; m++) {
      const int ro = (wm * 128 + m * 16 + lr) * 40 + lk * 8;
      ah[m] = *(const s16x8*)(sAh + ro);
      if constexpr (PASSES == 3) al[m] = *(const s16x8*)(sAl + ro);
    }
#pragma unroll
    for (int nt = 0; nt < 4; nt++) {
      const int ro = (wn * 64 + nt * 16 + lr) * 40 + lk * 8;
      s16x8 bh = *(const s16x8*)(sBh + ro);
#pragma unroll
      for (int m = 0; m < 8; m++) acc[m][nt] = mm_bf16(ah[m], bh, acc[m][nt]);
      if constexpr (PASSES == 3) {
        s16x8 bl = *(const s16x8*)(sBl + ro);
#pragma unroll
        for (int m = 0; m < 8; m++) acc[m][nt] = mm_bf16(ah[m], bl, acc[m][nt]);
#pragma unroll
        for (int m = 0; m < 8; m++) acc[m][nt] = mm_bf16(al[m], bh, acc[m][nt]);
      }
    }
  }

  if constexpr (EPI == 2) {
    // --- scores epilogue: tile is S^T [256 kv][128 q]; chunk = wave's 128 kv ---
    const int c = blockIdx.x * 2 + wm;
#pragma unroll
    for (int nt = 0; nt < 4; nt++) {
      const int q_l = wn * 64 + nt * 16 + lr;
      const float* arow = Adj + (size_t)(nbase + q_l) * (size_t)M + mbase + wm * 128 + lk * 4;
      float4 a4[8];
#pragma unroll
      for (int mt = 0; mt < 8; mt++) a4[mt] = *(const float4*)(arow + mt * 16);
      float mx = -3.4e38f;
#pragma unroll
      for (int mt = 0; mt < 8; mt++)
#pragma unroll
        for (int r = 0; r < 4; r++) {
          float s = acc[mt][nt][r] * ((const float*)&a4[mt])[r] * scale;
          acc[mt][nt][r] = s;
          mx = fmaxf(mx, s);
        }
      mx = fmaxf(mx, __shfl_xor(mx, 16));
      mx = fmaxf(mx, __shfl_xor(mx, 32));
      float sm = 0.f;
#pragma unroll
      for (int mt = 0; mt < 8; mt++)
#pragma unroll
        for (int r = 0; r < 4; r++) {
          float p = __expf(acc[mt][nt][r] - mx);
          acc[mt][nt][r] = p;
          sm += p;
        }
      sm += __shfl_xor(sm, 16);
      sm += __shfl_xor(sm, 32);
      if (lane < 16) {
        mC[(size_t)c * N + nbase + wn * 64 + nt * 16 + lane] = mx;
        lC[(size_t)c * N + nbase + wn * 64 + nt * 16 + lane] = sm;
      }
    }
    // bounce P' [128 q][256 kv] through LDS (pitch 264), coalesced global write
    __syncthreads();                      // all waves done reading stage bufs
    u16* pb = lds;
#pragma unroll
    for (int nt = 0; nt < 4; nt++) {
      const int q_l = wn * 64 + nt * 16 + lr;
#pragma unroll
      for (int mt = 0; mt < 8; mt++) {
        const int kvo = wm * 128 + mt * 16 + lk * 4;
        u32 u0 = (u32)f2bf(acc[mt][nt][0]) | ((u32)f2bf(acc[mt][nt][1]) << 16);
        u32 u1 = (u32)f2bf(acc[mt][nt][2]) | ((u32)f2bf(acc[mt][nt][3]) << 16);
        *(uint2*)&pb[q_l * 264 + kvo] = make_uint2(u0, u1);
      }
    }
    __syncthreads();
    {
      const int q_r = tid >> 1, half = tid & 1;
      u16* dst = Pout + (size_t)(nbase + q_r) * (size_t)M + mbase + half * 128;
      const u16* srcp = &pb[q_r * 264 + half * 128];
#pragma unroll
      for (int i = 0; i < 16; i++) ((uint4*)dst)[i] = *(const uint4*)(srcp + i * 8);
    }
  } else {
    float* cfp = Cf;
    if constexpr (KSPLIT > 1) {
      if (blockIdx.z == 1) cfp = Cf1;
      else if (blockIdx.z == 2) cfp = Cf2;
      else if (blockIdx.z == 3) cfp = Cf3;
    }
#pragma unroll
    for (int mt = 0; mt < 8; mt++)
#pragma unroll
      for (int nt = 0; nt < 4; nt++) {
        const int grow = mbase + wm * 128 + mt * 16 + lk * 4;
        const int gcol = nbase + wn * 64 + nt * 16 + lr;
#pragma unroll
        for (int r = 0; r < 4; r++)
          cfp[(size_t)(grow + r) * N + gcol] = acc[mt][nt][r];
      }
  }
}

// ---------------- projections GEMM (proven 128x128 template) ----------------

template<int EPI, int PASSES, int FUSEW, int KSPLIT>
__launch_bounds__(256, 4)
__global__ void gemm_bt(const u16* __restrict__ Ahi, const u16* __restrict__ Alo,
                        const u16* __restrict__ Bhi, const u16* __restrict__ Blo,
                        int M, int N, int K,
                        u16* __restrict__ C0, u16* __restrict__ C1)
{
  constexpr int BUF = 128 * 40;
  __shared__ __align__(16) u16 lds[BUF * 4];

  u16* sAh = lds;
  u16* sAl = lds + BUF;
  u16* sBh = lds + 2 * BUF;
  u16* sBl = lds + 3 * BUF;

  const int tid = threadIdx.x, lane = tid & 63, wid = tid >> 6;
  const int wm = wid & 1, wn = wid >> 1;
  const int lr = lane & 15, lk = lane >> 4;
  const int mbase = blockIdx.x * 128;
  const int w = blockIdx.y >> 2;
  const int nbase = (blockIdx.y & 3) * 128;
  const u16 *bhp = Bhi + (size_t)w * 262144, *blp = Blo + (size_t)w * 262144;
  u16 *c0 = C0 + (size_t)w * 4194304, *c1 = C1 + (size_t)w * 4194304;
  const int srow = tid >> 1, shalf = tid & 1;
  const size_t Ks = (size_t)K;

  f32x4 acc[4][4] = {};

  for (int kt = 0; kt < K; kt += 32) {
    const size_t aoff = (size_t)(mbase + srow) * Ks + kt + shalf * 16;
    const size_t boff = (size_t)(nbase + srow) * Ks + kt + shalf * 16;
    uint4 vah0 = *(const uint4*)(Ahi + aoff), vah1 = *(const uint4*)(Ahi + aoff + 8);
    uint4 vbh0 = *(const uint4*)(bhp + boff), vbh1 = *(const uint4*)(bhp + boff + 8);
    uint4 val0 = *(const uint4*)(Alo + aoff), val1 = *(const uint4*)(Alo + aoff + 8);
    uint4 vbl0 = *(const uint4*)(blp + boff), vbl1 = *(const uint4*)(blp + boff + 8);
    __syncthreads();
    const int so = srow * 40 + shalf * 16;
    *(uint4*)(sAh + so) = vah0; *(uint4*)(sAh + so + 8) = vah1;
    *(uint4*)(sBh + so) = vbh0; *(uint4*)(sBh + so + 8) = vbh1;
    *(uint4*)(sAl + so) = val0; *(uint4*)(sAl + so + 8) = val1;
    *(uint4*)(sBl + so) = vbl0; *(uint4*)(sBl + so + 8) = vbl1;
    __syncthreads();

    s16x8 ah[4], bh[4], al[4], bl[4];
#pragma unroll
    for (int t = 0; t < 4; t++) {
      ah[t] = *(const s16x8*)(sAh + (wm * 64 + t * 16 + lr) * 40 + lk * 8);
      bh[t] = *(const s16x8*)(sBh + (wn * 64 + t * 16 + lr) * 40 + lk * 8);
      al[t] = *(const s16x8*)(sAl + (wm * 64 + t * 16 + lr) * 40 + lk * 8);
      bl[t] = *(const s16x8*)(sBl + (wn * 64 + t * 16 + lr) * 40 + lk * 8);
    }
#pragma unroll
    for (int mt = 0; mt < 4; mt++)
#pragma unroll
      for (int nt = 0; nt < 4; nt++) {
        acc[mt][nt] = mm_bf16(ah[mt], bh[nt], acc[mt][nt]);
        acc[mt][nt] = mm_bf16(ah[mt], bl[nt], acc[mt][nt]);
        acc[mt][nt] = mm_bf16(al[mt], bh[nt], acc[mt][nt]);
      }
  }

#pragma unroll
  for (int mt = 0; mt < 4; mt++)
#pragma unroll
    for (int nt = 0; nt < 4; nt++) {
      const int grow = mbase + wm * 64 + mt * 16 + lk * 4;
      const int gcol = nbase + wn * 64 + nt * 16 + lr;
#pragma unroll
      for (int r = 0; r < 4; r++) {
        float c = acc[mt][nt][r];
        size_t o = (size_t)(grow + r) * N + gcol;
        u16 h = f2bf(c);
        c0[o] = h;
        c1[o] = f2bf(c - bf2f(h));
      }
    }
}

// ---------------- softmax cross-chunk reduce ----------------

__global__ void k_reduce(const float* __restrict__ mC, const float* __restrict__ lC, float* __restrict__ F,
                         int NQ, int NC) {
  const int q = blockIdx.x * 256 + threadIdx.x;
  if (q >= NQ) return;
  float mf = -3.4e38f;
  for (int c = 0; c < NC; c++) mf = fmaxf(mf, mC[(size_t)c * NQ + q]);
  float L = 0.f;
  for (int c = 0; c < NC; c++) L += lC[(size_t)c * NQ + q] * __expf(mC[(size_t)c * NQ + q] - mf);
  const float inv = 1.0f / L;
  for (int c = 0; c < NC; c++) F[(size_t)c * NQ + q] = __expf(mC[(size_t)c * NQ + q] - mf) * inv;
}

// out += p1 + p2 + p3  (fp32, fixed order -> deterministic)
__global__ void k_sumout3(float* __restrict__ out, const float* __restrict__ p1,
                          const float* __restrict__ p2, const float* __restrict__ p3, int n4) {
  int i = blockIdx.x * 256 + threadIdx.x;
  if (i >= n4) return;
  float4 o = ((const float4*)out)[i];
  float4 a = ((const float4*)p1)[i];
  float4 b = ((const float4*)p2)[i];
  float4 c = ((const float4*)p3)[i];
  o.x += a.x + b.x + c.x; o.y += a.y + b.y + c.y;
  o.z += a.z + b.z + c.z; o.w += a.w + b.w + c.w;
  ((float4*)out)[i] = o;
}

// ---------------- launcher ----------------

extern "C" void kernel_launch(void* const* d_in, const int* in_sizes, int n_in,
                              void* d_out, int out_size, void* d_ws, size_t ws_size,
                              hipStream_t stream) {
  const float* H  = (const float*)d_in[0];
  const float* Aj = (const float*)d_in[1];
  const float* Wq = (const float*)d_in[2];
  const float* Wk = (const float*)d_in[3];
  const float* Wv = (const float*)d_in[4];
  float* out = (float*)d_out;
  const int NN = 8192, DD = 512;

  char* ws = (char*)d_ws;
  size_t off = 0;
  auto alloc = [&](size_t bytes) -> void* {
    void* p = ws + off;
    off += (bytes + 255) & ~(size_t)255;
    return p;
  };
  u16* Pbuf  = (u16*)alloc((size_t)NN * NN * 2);           // 128 MB
  u16* Hhi   = (u16*)alloc((size_t)NN * DD * 2);
  u16* Hlo   = (u16*)alloc((size_t)NN * DD * 2);
  u16* WThi  = (u16*)alloc((size_t)3 * DD * DD * 2);
  u16* WTlo  = (u16*)alloc((size_t)3 * DD * DD * 2);
  u16* PRhi  = (u16*)alloc((size_t)3 * NN * DD * 2);       // [HQ|HK|HV] hi
  u16* PRlo  = (u16*)alloc((size_t)3 * NN * DD * 2);
  u16* HVthi = (u16*)alloc((size_t)NN * DD * 2);
  float* mC  = (float*)alloc((size_t)64 * NN * 4);
  float* lC  = (float*)alloc((size_t)64 * NN * 4);
  float* Ft  = (float*)alloc((size_t)64 * NN * 4);
  if (off > ws_size) return;  // workspace too small -> visible failure

  u16* HQhi = PRhi;                 u16* HQlo = PRlo;
  u16* HKhi = PRhi + (size_t)NN*DD; u16* HKlo = PRlo + (size_t)NN*DD;
  u16* HVhi = PRhi + (size_t)2*NN*DD;

  // K-split partials for PV: alias the dead region (Hhi..PRlo ~67 MB dead by then)
  float* part1 = (float*)Hhi;                              // 3 x 16.78 MB
  float* part2 = part1 + (size_t)NN * DD;
  float* part3 = part2 + (size_t)NN * DD;

  const float scl = 1.0f / sqrtf((float)DD);

  k_split<<<4096, 256, 0, stream>>>(H, Hhi, Hlo, NN * DD / 4);
  k_prepW<<<3072, 256, 0, stream>>>(Wq, Wk, Wv, WThi, WTlo);

  // fused Q/K/V projections: grid y = {w}*4 + {n-tile}
  dim3 gP(64, 12);
  gemm_bt<0, 3, 1, 1><<<gP, 256, 0, stream>>>(Hhi, Hlo, WThi, WTlo, NN, DD, DD, PRhi, PRlo);

  dim3 gT(128, 8);
  k_transpose<<<gT, 256, 0, stream>>>(HVhi, HVthi, NN, DD);

  // scores: 256x128 tiles, 3-pass; chunk = 128 kv (NC = 64 unchanged)
  dim3 gS(32, 64);
  k_big<2, 3, 1><<<gS, 256, 0, stream>>>(HKhi, HKlo, HQhi, HQlo, NN, NN, DD,
                                         nullptr, nullptr, nullptr, nullptr,
                                         Aj, mC, lC, Pbuf, nullptr, scl);

  k_reduce<<<32, 256, 0, stream>>>(mC, lC, Ft, NN, 64);

  // PV: out = (P'*F) @ HVt^T, 1-pass, 256x128 tiles, K split 4-way
  dim3 gO(32, 4, 4);
  k_big<3, 1, 4><<<gO, 256, 0, stream>>>(Pbuf, nullptr, HVthi, nullptr, NN, DD, NN,
                                         out, part1, part2, part3,
                                         nullptr, nullptr, nullptr, nullptr, Ft, 0.f);

  k_sumout3<<<4096, 256, 0, stream>>>(out, part1, part2, part3, NN * DD / 4);
}